// Round 1
// baseline (2811.844 us; speedup 1.0000x reference)
//
#include <hip/hip_runtime.h>

#define NB 256
#define NT 1000
#define ND 64
#define NH 128

__device__ __forceinline__ float sigmoid_f(float x) {
    float e = __builtin_amdgcn_exp2f(-1.4426950408889634f * x);
    return __builtin_amdgcn_rcpf(1.0f + e);
}
__device__ __forceinline__ float tanh_f(float x) {
    float e = __builtin_amdgcn_exp2f(-2.8853900817779268f * x);
    return 2.0f * __builtin_amdgcn_rcpf(1.0f + e) - 1.0f;
}

__global__ __launch_bounds__(512) void gruode_fused(
    const float* __restrict__ x,      // (B,T,D)
    const float* __restrict__ tps,    // (T)
    const int*   __restrict__ mask,   // (B,T)
    const float* __restrict__ W_ih,   // (384,64)
    const float* __restrict__ W_hh,   // (384,128)
    const float* __restrict__ b_ih,   // (384)
    const float* __restrict__ b_hh,   // (384)
    const float* __restrict__ nW1,    // (128,128)
    const float* __restrict__ nb1,    // (128)
    const float* __restrict__ nW2,    // (128,128)
    const float* __restrict__ nb2,    // (128)
    const float* __restrict__ W_out,  // (128,128)
    const float* __restrict__ b_out,  // (128)
    float* __restrict__ out)          // (B,128)
{
    __shared__ float sh_h[NH];
    __shared__ float sh_tmp[NH];
    __shared__ float sh_ode[NH];

    const int tid = threadIdx.x;
    const int j   = tid >> 2;   // output row 0..127
    const int q   = tid & 3;    // K-quarter
    const int kb  = q * 32;     // K range for H-dots
    const int kbi = q * 16;     // K range for D-dots
    const int b   = blockIdx.x;

    // ---- stage all weights into registers (one-time) ----
    float4 w1v[8], w2v[8], whr[8], whz[8], whn[8];
    float4 wir[4], wiz[4], win[4];
#pragma unroll
    for (int i = 0; i < 8; ++i) {
        w1v[i] = *(const float4*)(nW1  + (j      )*NH + kb + i*4);
        w2v[i] = *(const float4*)(nW2  + (j      )*NH + kb + i*4);
        whr[i] = *(const float4*)(W_hh + (j      )*NH + kb + i*4);
        whz[i] = *(const float4*)(W_hh + (j + 128)*NH + kb + i*4);
        whn[i] = *(const float4*)(W_hh + (j + 256)*NH + kb + i*4);
    }
#pragma unroll
    for (int i = 0; i < 4; ++i) {
        wir[i] = *(const float4*)(W_ih + (j      )*ND + kbi + i*4);
        wiz[i] = *(const float4*)(W_ih + (j + 128)*ND + kbi + i*4);
        win[i] = *(const float4*)(W_ih + (j + 256)*ND + kbi + i*4);
    }
    const float bb1   = nb1[j];
    const float bb2   = nb2[j];
    const float brz_r = b_ih[j]       + b_hh[j];
    const float brz_z = b_ih[j + 128] + b_hh[j + 128];
    const float bin_n = b_ih[j + 256];
    const float bhn_n = b_hh[j + 256];

    if (tid < NH) sh_h[tid] = 0.0f;
    __syncthreads();

    float hlast = 0.0f;
    int   seen  = 0;
    float tprev = 0.0f;

    for (int s = 0; s < NT; ++s) {
        const int   m    = mask[b * NT + s];
        const float tcur = tps[s];
        const float dt   = (s == 0) ? 0.0f : (tcur - tprev);
        tprev = tcur;
        const float dte  = seen ? dt : 0.0f;   // r_fill freeze: uniform per block

        // prefetch x_t (latency hidden under node stages)
        const float* xr = x + ((size_t)b * NT + s) * ND + kbi;
        float4 xv[4];
#pragma unroll
        for (int i = 0; i < 4; ++i) xv[i] = *(const float4*)(xr + i*4);

        const float hj = sh_h[j];
        float hode_j;
        const float* hsrc;

        if (dte != 0.0f) {
            // stage 1: tmp = tanh(W1 h + b1)
            float a1 = 0.0f;
#pragma unroll
            for (int i = 0; i < 8; ++i) {
                const float4 hv = *(const float4*)(sh_h + kb + i*4);
                a1 += w1v[i].x*hv.x + w1v[i].y*hv.y + w1v[i].z*hv.z + w1v[i].w*hv.w;
            }
            a1 += __shfl_xor(a1, 1);
            a1 += __shfl_xor(a1, 2);
            const float t1 = tanh_f(a1 + bb1);
            if (q == 0) sh_tmp[j] = t1;
            __syncthreads();

            // stage 2: h_ode = h + dt * (W2 tmp + b2)
            float a2 = 0.0f;
#pragma unroll
            for (int i = 0; i < 8; ++i) {
                const float4 hv = *(const float4*)(sh_tmp + kb + i*4);
                a2 += w2v[i].x*hv.x + w2v[i].y*hv.y + w2v[i].z*hv.z + w2v[i].w*hv.w;
            }
            a2 += __shfl_xor(a2, 1);
            a2 += __shfl_xor(a2, 2);
            hode_j = hj + dte * (a2 + bb2);
            if (q == 0) sh_ode[j] = hode_j;
            __syncthreads();
            hsrc = sh_ode;
        } else {
            hode_j = hj;
            hsrc = sh_h;
        }

        // stage 3: GRU cell
        float ar = 0.0f, az = 0.0f, an = 0.0f;
#pragma unroll
        for (int i = 0; i < 8; ++i) {
            const float4 hv = *(const float4*)(hsrc + kb + i*4);
            ar += whr[i].x*hv.x + whr[i].y*hv.y + whr[i].z*hv.z + whr[i].w*hv.w;
            az += whz[i].x*hv.x + whz[i].y*hv.y + whz[i].z*hv.z + whz[i].w*hv.w;
            an += whn[i].x*hv.x + whn[i].y*hv.y + whn[i].z*hv.z + whn[i].w*hv.w;
        }
        float gr = 0.0f, gz = 0.0f, gn = 0.0f;
#pragma unroll
        for (int i = 0; i < 4; ++i) {
            gr += wir[i].x*xv[i].x + wir[i].y*xv[i].y + wir[i].z*xv[i].z + wir[i].w*xv[i].w;
            gz += wiz[i].x*xv[i].x + wiz[i].y*xv[i].y + wiz[i].z*xv[i].z + wiz[i].w*xv[i].w;
            gn += win[i].x*xv[i].x + win[i].y*xv[i].y + win[i].z*xv[i].z + win[i].w*xv[i].w;
        }
        float sr = ar + gr, sz = az + gz;
        sr += __shfl_xor(sr, 1); sr += __shfl_xor(sr, 2);
        sz += __shfl_xor(sz, 1); sz += __shfl_xor(sz, 2);
        an += __shfl_xor(an, 1); an += __shfl_xor(an, 2);
        gn += __shfl_xor(gn, 1); gn += __shfl_xor(gn, 2);

        const float r = sigmoid_f(sr + brz_r);
        const float z = sigmoid_f(sz + brz_z);
        const float n = tanh_f(gn + bin_n + r * (an + bhn_n));
        const float hnew = m ? ((1.0f - z) * n + z * hode_j) : hode_j;

        __syncthreads();           // all reads of sh_h/hsrc complete
        if (q == 0) sh_h[j] = hnew;
        if (m) hlast = hnew;       // track h at last observed step
        seen |= m;
        __syncthreads();           // h visible for next step
    }

    // epilogue: out = W_out @ h_last + b_out
    if (q == 0) sh_tmp[j] = hlast;
    __syncthreads();
    float ao = 0.0f;
#pragma unroll
    for (int i = 0; i < 8; ++i) {
        const float4 wv = *(const float4*)(W_out + j*NH + kb + i*4);
        const float4 hv = *(const float4*)(sh_tmp + kb + i*4);
        ao += wv.x*hv.x + wv.y*hv.y + wv.z*hv.z + wv.w*hv.w;
    }
    ao += __shfl_xor(ao, 1);
    ao += __shfl_xor(ao, 2);
    if (q == 0) out[b*NH + j] = ao + b_out[j];
}

extern "C" void kernel_launch(void* const* d_in, const int* in_sizes, int n_in,
                              void* d_out, int out_size, void* d_ws, size_t ws_size,
                              hipStream_t stream) {
    const float* x     = (const float*)d_in[0];
    const float* tps   = (const float*)d_in[1];
    const int*   mask  = (const int*)  d_in[2];
    const float* W_ih  = (const float*)d_in[3];
    const float* W_hh  = (const float*)d_in[4];
    const float* b_ih  = (const float*)d_in[5];
    const float* b_hh  = (const float*)d_in[6];
    const float* nW1   = (const float*)d_in[7];
    const float* nb1   = (const float*)d_in[8];
    const float* nW2   = (const float*)d_in[9];
    const float* nb2   = (const float*)d_in[10];
    const float* W_out = (const float*)d_in[11];
    const float* b_out = (const float*)d_in[12];
    float* out = (float*)d_out;

    gruode_fused<<<dim3(NB), dim3(512), 0, stream>>>(
        x, tps, mask, W_ih, W_hh, b_ih, b_hh,
        nW1, nb1, nW2, nb2, W_out, b_out, out);
}